// Round 7
// baseline (356.162 us; speedup 1.0000x reference)
//
#include <hip/hip_runtime.h>
#include <stdint.h>

// Problem constants
#define BT     32768      // B*T rows
#define CIN    512
#define NE     640        // GROUP*ENTRY
#define ENTRY  320
#define DD     256        // COUT/GROUP
#define MROWS  32         // rows per block
#define TPB    256        // 4 waves

using bf16x8 = __attribute__((ext_vector_type(8))) short;
using f32x4  = __attribute__((ext_vector_type(4))) float;

// LDS layout (bytes):
//   y  bf16 [32 rows][640], XOR-swizzled : [0, 40960)
//   pS f32 [32 rows][4 waves]            : [40960, 41472)
// 41472 B/block -> 3 blocks/CU (124.4 KB). x never touches LDS.
#define PS_OFF     40960
#define SMEM_BYTES 41472

__device__ __forceinline__ unsigned short f2b(float f) {
    union { float f; uint32_t u; } v; v.f = f;
    uint32_t u = v.u;
    return (unsigned short)((u + 0x7FFFu + ((u >> 16) & 1u)) >> 16);
}

// 8x f32 -> bf16x8, pure C RNE (proven path from rounds 0-5; no inline asm)
__device__ __forceinline__ bf16x8 cvt8(float4 a, float4 b) {
    bf16x8 t;
    t[0] = (short)f2b(a.x); t[1] = (short)f2b(a.y);
    t[2] = (short)f2b(a.z); t[3] = (short)f2b(a.w);
    t[4] = (short)f2b(b.x); t[5] = (short)f2b(b.y);
    t[6] = (short)f2b(b.z); t[7] = (short)f2b(b.w);
    return t;
}

// Prep into MFMA-fragment order (verified r5):
//   WpB2 [ks][e][kk]   : WpB2[ks*20480 + e*32 + kk] = bf16(Wp[e][ks*32+kk])
//   cbT2 [g][ks][n][kk]: cbT2[((g*10+ks)*256 + n)*32 + kk] = bf16(cb[g][ks*32+kk][n])
__global__ void prep_kernel(const float* __restrict__ Wp, const float* __restrict__ cb,
                            unsigned short* __restrict__ WpB2, unsigned short* __restrict__ cbT2) {
    int i = blockIdx.x * blockDim.x + threadIdx.x;
    if (i < NE * CIN) {
        int ks  = i / 20480;
        int rem = i - ks * 20480;
        int e   = rem >> 5;
        int kk  = rem & 31;
        WpB2[i] = f2b(Wp[e * CIN + ks * 32 + kk]);
    } else {
        int o = i - NE * CIN;
        if (o < 2 * ENTRY * DD) {
            int kk = o & 31;
            int t  = o >> 5;
            int n  = t & 255;
            int t2 = t >> 8;
            int ks = t2 % 10;
            int g  = t2 / 10;
            cbT2[o] = f2b(cb[(g * ENTRY + ks * 32 + kk) * DD + n]);
        }
    }
}

#define MFMA16(d, a, b) d = __builtin_amdgcn_mfma_f32_16x16x32_bf16(a, b, d, 0, 0, 0)

__global__ __launch_bounds__(TPB, 3) void fused_kernel(
    const float* __restrict__ x, const float* __restrict__ bp,
    const float* __restrict__ gum, const unsigned short* __restrict__ WpB2,
    const unsigned short* __restrict__ cbT2, float* __restrict__ out) {

    extern __shared__ char smem[];
    float* pS = (float*)(smem + PS_OFF);

    const int tid = threadIdx.x;
    const int w  = tid >> 6;     // wave 0..3 (col-slice)
    const int l  = tid & 63;
    const int q  = l >> 4;       // quad 0..3
    const int ln = l & 15;
    const int rowbase = blockIdx.x * MROWS;
    const int swz = (ln & 7) << 4;
    const int blane = ln * 32 + q * 8;

    // x fragment source: lane (q,ln) supplies rows ln / 16+ln, k = ks*32 + q*8 .. +7
    const float* xbase = x + (size_t)(rowbase + ln) * CIN + q * 8;

    float pr[8];
#pragma unroll
    for (int i = 0; i < 8; ++i) pr[i] = 0.f;

    const f32x4 fz = {0.f, 0.f, 0.f, 0.f};

    // ============ Phases 1+2, two half-passes over the entry axis ============
#pragma unroll 1
    for (int h = 0; h < 2; ++h) {
        const unsigned short* bh = WpB2 + (h * 320 + w * 80) * 32 + blane;  // +ks*20480 +ct*512

        f32x4 acc[2][5];
#pragma unroll
        for (int rt = 0; rt < 2; ++rt)
#pragma unroll
            for (int ct = 0; ct < 5; ++ct) acc[rt][ct] = fz;

        bf16x8 pA[5], pB[5];
        bf16x8 afA0, afA1, afB0, afB1;
        // prologue: ks=0
        {
            float4 r0 = *(const float4*)(xbase);
            float4 r1 = *(const float4*)(xbase + 4);
            float4 r2 = *(const float4*)(xbase + 16 * CIN);
            float4 r3 = *(const float4*)(xbase + 16 * CIN + 4);
#pragma unroll
            for (int ct = 0; ct < 5; ++ct) pA[ct] = *(const bf16x8*)(bh + ct * 512);
            afA0 = cvt8(r0, r1); afA1 = cvt8(r2, r3);
        }

#pragma unroll 1
        for (int ks2 = 0; ks2 < 16; ks2 += 2) {
            // prefetch ks2+1 into B set, MFMA with A set
            {
                const unsigned short* pk = bh + (ks2 + 1) * 20480;
                const float* xp = xbase + (ks2 + 1) * 32;
                float4 r0 = *(const float4*)(xp);
                float4 r1 = *(const float4*)(xp + 4);
                float4 r2 = *(const float4*)(xp + 16 * CIN);
                float4 r3 = *(const float4*)(xp + 16 * CIN + 4);
#pragma unroll
                for (int ct = 0; ct < 5; ++ct) pB[ct] = *(const bf16x8*)(pk + ct * 512);
#pragma unroll
                for (int ct = 0; ct < 5; ++ct) {
                    MFMA16(acc[0][ct], afA0, pA[ct]);
                    MFMA16(acc[1][ct], afA1, pA[ct]);
                }
                afB0 = cvt8(r0, r1); afB1 = cvt8(r2, r3);
            }
            // prefetch ks2+2 into A set, MFMA with B set
            {
                float4 r0, r1, r2, r3;
                if (ks2 + 2 < 16) {
                    const unsigned short* pk = bh + (ks2 + 2) * 20480;
                    const float* xp = xbase + (ks2 + 2) * 32;
                    r0 = *(const float4*)(xp);
                    r1 = *(const float4*)(xp + 4);
                    r2 = *(const float4*)(xp + 16 * CIN);
                    r3 = *(const float4*)(xp + 16 * CIN + 4);
#pragma unroll
                    for (int ct = 0; ct < 5; ++ct) pA[ct] = *(const bf16x8*)(pk + ct * 512);
                }
#pragma unroll
                for (int ct = 0; ct < 5; ++ct) {
                    MFMA16(acc[0][ct], afB0, pB[ct]);
                    MFMA16(acc[1][ct], afB1, pB[ct]);
                }
                if (ks2 + 2 < 16) { afA0 = cvt8(r0, r1); afA1 = cvt8(r2, r3); }
            }
        }

        // ---- Phase 2h: exp + y -> LDS (swizzled, wave-private cols) + partial sums ----
        float bpv[5];
#pragma unroll
        for (int ct = 0; ct < 5; ++ct) bpv[ct] = bp[h * 320 + w * 80 + ct * 16 + ln];

#pragma unroll
        for (int ri = 0; ri < 8; ++ri) {
            int rt = ri >> 2, r = ri & 3;
            int row = rt * 16 + q * 4 + r;
            const float* pg = gum + (size_t)(rowbase + row) * NE + h * 320 + w * 80 + ln;
            int ybase = row * 1280;
            int yswz  = (row & 7) << 4;
            float p = 0.f;
#pragma unroll
            for (int ct = 0; ct < 5; ++ct) {
                int colb = (h * 320 + w * 80 + ct * 16 + ln) * 2;   // byte offset in row
                float v = acc[rt][ct][r] + bpv[ct] + pg[ct * 16];
                float e = __expf(v);
                *(unsigned short*)(smem + ybase + (colb ^ yswz)) = f2b(e);
                p += e;
            }
            p += __shfl_xor(p, 1);
            p += __shfl_xor(p, 2);
            p += __shfl_xor(p, 4);
            p += __shfl_xor(p, 8);
            pr[ri] += p;
        }
    }

    // write per-wave partial sums (unique slots, no atomics, no init)
    if (ln == 0) {
#pragma unroll
        for (int ri = 0; ri < 8; ++ri) {
            int row = (ri >> 2) * 16 + q * 4 + (ri & 3);
            pS[row * 4 + w] = pr[ri];
        }
    }

    // prefetch cb ks=0 fragments; latency absorbed by the single barrier
    const int g  = w >> 1;
    const int nb = (w & 1) * 128;
    const unsigned short* cptr = cbT2 + (size_t)g * 81920 + nb * 32 + blane;  // +ks*8192 +ct*512
    bf16x8 cA[8], cB[8];
#pragma unroll
    for (int ct = 0; ct < 8; ++ct) cA[ct] = *(const bf16x8*)(cptr + ct * 512);

    __syncthreads();   // the kernel's only barrier: y + pS visible to all waves

    // ============ Phase 3: out = (y @ cb) / S (cb direct from L2, pipelined) ============
    f32x4 acc2[2][8];
#pragma unroll
    for (int rt = 0; rt < 2; ++rt)
#pragma unroll
        for (int ct = 0; ct < 8; ++ct) acc2[rt][ct] = fz;

    const int yB = ln * 1280;   // rows ln and 16+ln (+20480)
    bf16x8 yA0, yA1, yB0, yB1;
    {
        const int at = (g * 640 + q * 16) ^ swz;
        yA0 = *(const bf16x8*)(smem + yB + at);
        yA1 = *(const bf16x8*)(smem + yB + 20480 + at);
    }

#pragma unroll 1
    for (int ks2 = 0; ks2 < 10; ks2 += 2) {
        {
            const unsigned short* pk = cptr + (ks2 + 1) * 8192;
#pragma unroll
            for (int ct = 0; ct < 8; ++ct) cB[ct] = *(const bf16x8*)(pk + ct * 512);
            const int at = (g * 640 + (ks2 + 1) * 64 + q * 16) ^ swz;
            yB0 = *(const bf16x8*)(smem + yB + at);
            yB1 = *(const bf16x8*)(smem + yB + 20480 + at);
        }
#pragma unroll
        for (int ct = 0; ct < 8; ++ct) {
            MFMA16(acc2[0][ct], yA0, cA[ct]);
            MFMA16(acc2[1][ct], yA1, cA[ct]);
        }
        if (ks2 + 2 < 10) {
            const unsigned short* pk = cptr + (ks2 + 2) * 8192;
#pragma unroll
            for (int ct = 0; ct < 8; ++ct) cA[ct] = *(const bf16x8*)(pk + ct * 512);
            const int at = (g * 640 + (ks2 + 2) * 64 + q * 16) ^ swz;
            yA0 = *(const bf16x8*)(smem + yB + at);
            yA1 = *(const bf16x8*)(smem + yB + 20480 + at);
        }
#pragma unroll
        for (int ct = 0; ct < 8; ++ct) {
            MFMA16(acc2[0][ct], yB0, cB[ct]);
            MFMA16(acc2[1][ct], yB1, cB[ct]);
        }
    }

    // epilogue: divide by softmax denom (sum of 4 wave-partials), store fp32
#pragma unroll
    for (int rt = 0; rt < 2; ++rt) {
#pragma unroll
        for (int r = 0; r < 4; ++r) {
            int row = rt * 16 + q * 4 + r;
            float4 sv = *(const float4*)(pS + row * 4);
            float inv = 1.0f / (sv.x + sv.y + sv.z + sv.w);
            size_t orow = (size_t)(rowbase + row) * 512;
#pragma unroll
            for (int ct = 0; ct < 8; ++ct) {
                int col = g * 256 + nb + ct * 16 + ln;
                out[orow + col] = acc2[rt][ct][r] * inv;
            }
        }
    }
}

extern "C" void kernel_launch(void* const* d_in, const int* in_sizes, int n_in,
                              void* d_out, int out_size, void* d_ws, size_t ws_size,
                              hipStream_t stream) {
    const float* x   = (const float*)d_in[0];
    const float* Wp  = (const float*)d_in[1];
    const float* bp  = (const float*)d_in[2];
    const float* cb  = (const float*)d_in[3];
    const float* gum = (const float*)d_in[4];
    float* out = (float*)d_out;

    unsigned short* WpB2 = (unsigned short*)d_ws;
    unsigned short* cbT2 = WpB2 + NE * CIN;

    int prep_total = NE * CIN + 2 * ENTRY * DD;
    prep_kernel<<<(prep_total + 255) / 256, 256, 0, stream>>>(Wp, cb, WpB2, cbT2);

    fused_kernel<<<dim3(BT / MROWS), dim3(TPB), SMEM_BYTES, stream>>>(x, bp, gum, WpB2, cbT2, out);
}